// Round 1
// baseline (368.159 us; speedup 1.0000x reference)
//
#include <hip/hip_runtime.h>

#define N_NODES 512
#define C_CH    128
#define D_DIM   16
#define S_SPEC  10

// Symmetrized coefficient tables (built on-device every launch; deterministic).
__device__ float g_coef3[816][112];  // [monomial a<=b<=j][(k*16)+o16]
__device__ float g_coef2[136][48];   // [pair a<=b][(k*16)+o16]
__device__ float g_coef1[16][16];    // [a][o16]

__device__ __forceinline__ int rfl(int v) { return __builtin_amdgcn_readfirstlane(v); }

// ---------------- precompute kernels ----------------

__global__ void build_coef3(const float* __restrict__ u0, const float* __restrict__ u1,
                            const float* __restrict__ u2, const float* __restrict__ u3) {
  int id = blockIdx.x * 64 + threadIdx.x;
  if (id >= 7 * 816) return;
  int k = id / 816;
  int m = id % 816;
  int mm = m, a = 0, b = 0;
  for (a = 0; a < 16; ++a) { int cnt = (16 - a) * (17 - a) / 2; if (mm < cnt) break; mm -= cnt; }
  for (b = a; b < 16; ++b) { int len = 16 - b; if (mm < len) break; mm -= len; }
  int j = b + mm;
  const float* us[4] = {u0, u1, u2, u3};
  const int dis[4]   = {1, 3, 5, 7};
  const int obase[4] = {0, 1, 4, 9};
  int P[6][3] = {{a,b,j},{a,j,b},{b,a,j},{b,j,a},{j,a,b},{j,b,a}};
  for (int ir = 0; ir < 4; ++ir) {
    int di = dis[ir];
    const float* u = us[ir];
    for (int i = 0; i < di; ++i) {
      float sum = 0.f;
      for (int p = 0; p < 6; ++p) {
        bool dup = false;
        for (int q = 0; q < p; ++q)
          if (P[q][0] == P[p][0] && P[q][1] == P[p][1] && P[q][2] == P[p][2]) { dup = true; break; }
        if (dup) continue;
        sum += u[(((P[p][0] * 16 + P[p][1]) * 16 + P[p][2]) * 7 + k) * di + i];
      }
      g_coef3[m][k * 16 + obase[ir] + i] = sum;
    }
  }
}

__global__ void build_coef2(const float* __restrict__ u0, const float* __restrict__ u1,
                            const float* __restrict__ u2, const float* __restrict__ u3) {
  int id = blockIdx.x * 64 + threadIdx.x;
  if (id >= 3 * 136) return;
  int k = id / 136;
  int m = id % 136;
  int mm = m, a = 0;
  for (a = 0; a < 16; ++a) { int len = 16 - a; if (mm < len) break; mm -= len; }
  int b = a + mm;
  const float* us[4] = {u0, u1, u2, u3};
  const int dis[4]   = {1, 3, 5, 7};
  const int obase[4] = {0, 1, 4, 9};
  for (int ir = 0; ir < 4; ++ir) {
    int di = dis[ir];
    const float* u = us[ir];
    for (int i = 0; i < di; ++i) {
      float sum = u[((a * 16 + b) * 3 + k) * di + i];
      if (a != b) sum += u[((b * 16 + a) * 3 + k) * di + i];
      g_coef2[m][k * 16 + obase[ir] + i] = sum;
    }
  }
}

__global__ void build_coef1(const float* __restrict__ u0, const float* __restrict__ u1,
                            const float* __restrict__ u2, const float* __restrict__ u3) {
  int a = threadIdx.x;
  if (a >= 16) return;
  const float* us[4] = {u0, u1, u2, u3};
  const int dis[4]   = {1, 3, 5, 7};
  const int obase[4] = {0, 1, 4, 9};
  for (int ir = 0; ir < 4; ++ir) {
    int di = dis[ir];
    for (int i = 0; i < di; ++i)
      g_coef1[a][obase[ir] + i] = us[ir][a * di + i];
  }
}

// ---------------- epilogue helper (per-half output columns) ----------------

template <int OB>
__device__ __forceinline__ void wlin_out(const float (*red)[17], const float* __restrict__ wlin,
                                         float* __restrict__ out, int n, int f) {
  constexpr int irOfA[16] = {0,1,1,1,2,2,2,2,2,3,3,3,3,3,3,3};
  constexpr int iOfA[16]  = {0,0,1,2,0,1,2,3,4,0,1,2,3,4,5,6};
  constexpr int diA[4]  = {1, 3, 5, 7};
  constexpr int ooff[4] = {0, 128, 512, 1152};
  float res[8];
#pragma unroll
  for (int oo = 0; oo < 8; ++oo) res[oo] = 0.f;
  for (int cc = 0; cc < 128; ++cc) {
    float wv[4];
#pragma unroll
    for (int ir = 0; ir < 4; ++ir) wv[ir] = wlin[(ir * C_CH + cc) * C_CH + f];
#pragma unroll
    for (int oo = 0; oo < 8; ++oo)
      res[oo] = fmaf(red[cc][OB + oo], wv[irOfA[OB + oo]], res[oo]);
  }
  const float inv = 0.08838834764831845f;  // 1/sqrt(128)
  size_t base = (size_t)n * 2048;
#pragma unroll
  for (int oo = 0; oo < 8; ++oo) {
    constexpr int dummy = 0; (void)dummy;
    int o = OB + oo;
    out[base + ooff[irOfA[OB + oo]] + (size_t)f * diA[irOfA[OB + oo]] + iOfA[OB + oo]] = res[oo] * inv;
    (void)o;
  }
}

// ---------------- main kernel ----------------

__global__ __launch_bounds__(256) void eqp_main(
    const float* __restrict__ x, const int* __restrict__ specie,
    const float* __restrict__ w1, const float* __restrict__ w2,
    const float* __restrict__ w3, const float* __restrict__ wlin,
    float* __restrict__ out) {
  constexpr int irOfA[16] = {0,1,1,1,2,2,2,2,2,3,3,3,3,3,3,3};
  __shared__ float xT[16][128];
  __shared__ float red[128][17];

  const int t = threadIdx.x;
  const int c = t & 127;
  const int h = t >> 7;          // wave-uniform half index (waves 0,1 -> 0; 2,3 -> 1)
  const int n = blockIdx.x;

  {  // stage x[n][c][:] transposed into LDS (stride-1 per lane on reads)
    const float* xp = x + ((size_t)n * C_CH + c) * D_DIM + h * 8;
    float4 v0 = *(const float4*)(xp);
    float4 v1 = *(const float4*)(xp + 4);
    float vs[8] = {v0.x, v0.y, v0.z, v0.w, v1.x, v1.y, v1.z, v1.w};
#pragma unroll
    for (int q = 0; q < 8; ++q) xT[h * 8 + q][c] = vs[q];
  }
  __syncthreads();

  const int s = specie[n];

  float acc[16];
#pragma unroll
  for (int o = 0; o < 16; ++o) acc[o] = 0.f;

  // ---- order 3: 816 symmetric monomials, halves split contiguously in j ----
  {
    float o3[112];
#pragma unroll
    for (int kk = 0; kk < 112; ++kk) o3[kk] = 0.f;
    int mab = 0;
    for (int a = 0; a < 16; ++a) {
      float xa = xT[a][c];
      for (int b = a; b < 16; ++b) {
        float xab = xa * xT[b][c];
        int len = 16 - b;
        int mid = b + ((len + ((a + b) & 1)) >> 1);
        int j0 = rfl(h == 0 ? b : mid);
        int j1 = rfl(h == 0 ? mid : 16);
        for (int j = j0; j < j1; ++j) {
          float mono = xab * xT[j][c];
          const float* srow = &g_coef3[mab + (j - b)][0];
#pragma unroll
          for (int kk = 0; kk < 112; ++kk) o3[kk] = fmaf(srow[kk], mono, o3[kk]);
        }
        mab += len;
      }
    }
    float w3c[28];
#pragma unroll
    for (int ir = 0; ir < 4; ++ir)
#pragma unroll
      for (int k = 0; k < 7; ++k)
        w3c[ir * 7 + k] = w3[((ir * S_SPEC + s) * 7 + k) * C_CH + c];
#pragma unroll
    for (int k = 0; k < 7; ++k)
#pragma unroll
      for (int o = 0; o < 16; ++o)
        acc[o] = fmaf(w3c[irOfA[o] * 7 + k], o3[k * 16 + o], acc[o]);
  }

  // ---- order 2: 136 symmetric pairs, halves split contiguously in b ----
  {
    float o2a[48];
#pragma unroll
    for (int kk = 0; kk < 48; ++kk) o2a[kk] = 0.f;
    int mp = 0;
    for (int a = 0; a < 16; ++a) {
      float xa = xT[a][c];
      int len = 16 - a;
      int mid = a + ((len + (a & 1)) >> 1);
      int b0 = rfl(h == 0 ? a : mid);
      int b1 = rfl(h == 0 ? mid : 16);
      for (int b = b0; b < b1; ++b) {
        float mono = xa * xT[b][c];
        const float* srow = &g_coef2[mp + (b - a)][0];
#pragma unroll
        for (int kk = 0; kk < 48; ++kk) o2a[kk] = fmaf(srow[kk], mono, o2a[kk]);
      }
      mp += len;
    }
    float w2c[12];
#pragma unroll
    for (int ir = 0; ir < 4; ++ir)
#pragma unroll
      for (int k = 0; k < 3; ++k)
        w2c[ir * 3 + k] = w2[((ir * S_SPEC + s) * 3 + k) * C_CH + c];
#pragma unroll
    for (int k = 0; k < 3; ++k)
#pragma unroll
      for (int o = 0; o < 16; ++o)
        acc[o] = fmaf(w2c[irOfA[o] * 3 + k], o2a[k * 16 + o], acc[o]);
  }

  // ---- order 1: halves split a-range ----
  {
    float o1[16];
#pragma unroll
    for (int o = 0; o < 16; ++o) o1[o] = 0.f;
    int a0 = rfl(h == 0 ? 0 : 8);
    int a1 = rfl(h == 0 ? 8 : 16);
    for (int a = a0; a < a1; ++a) {
      float xa = xT[a][c];
      const float* srow = &g_coef1[a][0];
#pragma unroll
      for (int o = 0; o < 16; ++o) o1[o] = fmaf(srow[o], xa, o1[o]);
    }
    float w1c[4];
#pragma unroll
    for (int ir = 0; ir < 4; ++ir) w1c[ir] = w1[(ir * S_SPEC + s) * C_CH + c];
#pragma unroll
    for (int o = 0; o < 16; ++o) acc[o] = fmaf(w1c[irOfA[o]], o1[o], acc[o]);
  }

  // ---- reduce the two halves, then channel-mix (wlin) ----
  if (h == 1) {
#pragma unroll
    for (int o = 0; o < 16; ++o) red[c][o] = acc[o];
  }
  __syncthreads();
  if (h == 0) {
#pragma unroll
    for (int o = 0; o < 16; ++o) red[c][o] += acc[o];
  }
  __syncthreads();

  if (h == 0) wlin_out<0>(red, wlin, out, n, c);
  else        wlin_out<8>(red, wlin, out, n, c);
}

// ---------------- launch ----------------

extern "C" void kernel_launch(void* const* d_in, const int* in_sizes, int n_in,
                              void* d_out, int out_size, void* d_ws, size_t ws_size,
                              hipStream_t stream) {
  const float* x      = (const float*)d_in[0];
  const int*   specie = (const int*)d_in[1];

  const float *u1s[4], *u2s[4], *u3s[4];
  // setup_inputs() dict order interleaves u1_i,u2_i,u3_i per irrep; detect defensively.
  if (in_sizes[3] == 768) {  // dict order: u1_0,u2_0,u3_0,u1_1,...
    for (int i = 0; i < 4; ++i) {
      u1s[i] = (const float*)d_in[2 + 3 * i];
      u2s[i] = (const float*)d_in[3 + 3 * i];
      u3s[i] = (const float*)d_in[4 + 3 * i];
    }
  } else {                   // grouped order: u1_0..u1_3,u2_0..u2_3,u3_0..u3_3
    for (int i = 0; i < 4; ++i) {
      u1s[i] = (const float*)d_in[2 + i];
      u2s[i] = (const float*)d_in[6 + i];
      u3s[i] = (const float*)d_in[10 + i];
    }
  }
  const float* w1   = (const float*)d_in[14];
  const float* w2   = (const float*)d_in[15];
  const float* w3   = (const float*)d_in[16];
  const float* wlin = (const float*)d_in[17];
  float* out = (float*)d_out;

  build_coef3<<<(7 * 816 + 63) / 64, 64, 0, stream>>>(u3s[0], u3s[1], u3s[2], u3s[3]);
  build_coef2<<<(3 * 136 + 63) / 64, 64, 0, stream>>>(u2s[0], u2s[1], u2s[2], u2s[3]);
  build_coef1<<<1, 64, 0, stream>>>(u1s[0], u1s[1], u1s[2], u1s[3]);
  eqp_main<<<N_NODES, 256, 0, stream>>>(x, specie, w1, w2, w3, wlin, out);
}